// Round 1
// baseline (228.903 us; speedup 1.0000x reference)
//
#include <hip/hip_runtime.h>

// g(act) lookup table: TN nodes over act in [0,1], entry i = (y_i, y_{i+1}-y_i)
#define TN 4096
#define BLOCK 256
#define ITERS 16   // patches per thread in main kernel

// Full reference math for one scalar activation value (runs only TN times).
__device__ float eval_g(float act,
                        const float* __restrict__ basis,
                        const float* __restrict__ w1,
                        const float* __restrict__ b1,
                        const float* __restrict__ w2,
                        const float* __restrict__ b2) {
    float feats[8];
#pragma unroll
    for (int b = 0; b < 8; ++b) {
        float s = 0.f;
#pragma unroll
        for (int k = 0; k < 4; ++k) {
            float d = act - basis[b * 4 + k];
            s = fmaf(d, d, s);
        }
        feats[b] = __expf(-s);   // GAMMA = 1
    }
    float out = b2[0];
#pragma unroll
    for (int j = 0; j < 16; ++j) {
        float u = b1[j];
#pragma unroll
        for (int b = 0; b < 8; ++b) u = fmaf(feats[b], w1[b * 16 + j], u);
        out = fmaf(tanhf(u), w2[j], out);
    }
    return out;
}

__global__ __launch_bounds__(BLOCK)
void fill_table_kernel(const float* __restrict__ basis,
                       const float* __restrict__ w1,
                       const float* __restrict__ b1,
                       const float* __restrict__ w2,
                       const float* __restrict__ b2,
                       float2* __restrict__ table) {
    int i = blockIdx.x * BLOCK + threadIdx.x;
    if (i >= TN) return;
    const float inv = 1.0f / (float)(TN - 1);
    float a0 = (float)i * inv;
    int ip = (i + 1 < TN) ? (i + 1) : (TN - 1);
    float a1 = (float)ip * inv;
    float y0 = eval_g(a0, basis, w1, b1, w2, b2);
    float y1 = eval_g(a1, basis, w1, b1, w2, b2);
    table[i] = make_float2(y0, y1 - y0);
}

__global__ __launch_bounds__(BLOCK)
void hybridconv_main(const float4* __restrict__ data,
                     const float* __restrict__ conv_w,
                     const float* __restrict__ conv_b,
                     const float2* __restrict__ gtable,
                     float* __restrict__ out, int n) {
    __shared__ float2 tab[TN];
    // cooperative table copy (16 KB of float2 pairs -> 32 KB LDS)
    for (int i = threadIdx.x; i < TN; i += BLOCK) tab[i] = gtable[i];
    __syncthreads();

    const float cw0 = conv_w[0], cw1 = conv_w[1], cw2 = conv_w[2], cw3 = conv_w[3];
    const float cb = conv_b[0];

    int base = blockIdx.x * (BLOCK * ITERS) + threadIdx.x;
#pragma unroll 4
    for (int k = 0; k < ITERS; ++k) {
        int idx = base + k * BLOCK;
        if (idx < n) {
            float4 d = data[idx];
            float logit = fmaf(d.x, cw0, fmaf(d.y, cw1, fmaf(d.z, cw2, fmaf(d.w, cw3, cb))));
            float e = __expf(-logit);                  // v_exp path
            float act = __builtin_amdgcn_rcpf(1.0f + e); // sigmoid, ~1 ulp
            float t = act * (float)(TN - 1);           // t in [0, 4095]
            unsigned int i = (unsigned int)t;          // trunc; act >= 0
            i = min(i, (unsigned int)(TN - 2));
            float frac = t - (float)i;
            float2 yd = tab[i];                        // ds_read_b64
            out[idx] = fmaf(frac, yd.y, yd.x);
        }
    }
}

extern "C" void kernel_launch(void* const* d_in, const int* in_sizes, int n_in,
                              void* d_out, int out_size, void* d_ws, size_t ws_size,
                              hipStream_t stream) {
    const float4* data  = (const float4*)d_in[0];
    const float* conv_w = (const float*)d_in[1];
    const float* conv_b = (const float*)d_in[2];
    const float* basis  = (const float*)d_in[3];
    const float* w1     = (const float*)d_in[4];
    const float* b1     = (const float*)d_in[5];
    const float* w2     = (const float*)d_in[6];
    const float* b2     = (const float*)d_in[7];
    float* out = (float*)d_out;
    float2* table = (float2*)d_ws;   // 32 KB scratch

    int n = out_size;  // N patches, one output each

    fill_table_kernel<<<dim3(TN / BLOCK), dim3(BLOCK), 0, stream>>>(
        basis, w1, b1, w2, b2, table);

    int per_block = BLOCK * ITERS;
    int blocks = (n + per_block - 1) / per_block;
    hybridconv_main<<<dim3(blocks), dim3(BLOCK), 0, stream>>>(
        data, conv_w, conv_b, table, out, n);
}

// Round 2
// 221.704 us; speedup vs baseline: 1.0325x; 1.0325x over previous
//
#include <hip/hip_runtime.h>

// g(act) lookup table: TN nodes over act in [0,1], entry i = (y_i, y_{i+1}-y_i).
// act = sigmoid(logit) is provably in [0,1]; tab[4095] = (y_max, 0) so no clamp
// is needed in the hot loop.
#define TN 4096
#define BLOCK 256
#define ITERS 32                  // patches per thread in main kernel
#define PER_BLOCK (BLOCK * ITERS) // 8192 patches per block

// Full reference math for one scalar activation value (runs only TN+tail times).
__device__ float eval_g(float act,
                        const float* __restrict__ basis,
                        const float* __restrict__ w1,
                        const float* __restrict__ b1,
                        const float* __restrict__ w2,
                        const float* __restrict__ b2) {
    float feats[8];
#pragma unroll
    for (int b = 0; b < 8; ++b) {
        float s = 0.f;
#pragma unroll
        for (int k = 0; k < 4; ++k) {
            float d = act - basis[b * 4 + k];
            s = fmaf(d, d, s);
        }
        feats[b] = __expf(-s);   // GAMMA = 1
    }
    float out = b2[0];
#pragma unroll
    for (int j = 0; j < 16; ++j) {
        float u = b1[j];
#pragma unroll
        for (int b = 0; b < 8; ++b) u = fmaf(feats[b], w1[b * 16 + j], u);
        out = fmaf(tanhf(u), w2[j], out);
    }
    return out;
}

__global__ __launch_bounds__(BLOCK)
void fill_table_kernel(const float* __restrict__ basis,
                       const float* __restrict__ w1,
                       const float* __restrict__ b1,
                       const float* __restrict__ w2,
                       const float* __restrict__ b2,
                       float2* __restrict__ table) {
    int i = blockIdx.x * BLOCK + threadIdx.x;
    if (i >= TN) return;
    const float inv = 1.0f / (float)(TN - 1);
    float a0 = (float)i * inv;
    int ip = (i + 1 < TN) ? (i + 1) : (TN - 1);
    float a1 = (float)ip * inv;
    float y0 = eval_g(a0, basis, w1, b1, w2, b2);
    float y1 = eval_g(a1, basis, w1, b1, w2, b2);
    table[i] = make_float2(y0, y1 - y0);
}

// Hot kernel: assumes grid covers exactly blocks*PER_BLOCK patches (no bounds
// check). Remainder patches handled by hybridconv_tail.
__global__ __launch_bounds__(BLOCK)
void hybridconv_main(const float4* __restrict__ data,
                     const float* __restrict__ conv_w,
                     const float* __restrict__ conv_b,
                     const float2* __restrict__ gtable,
                     float* __restrict__ out) {
    __shared__ __align__(16) float2 tab[TN];
    // cooperative table copy, float4-wide: 2048 float4 / 256 threads = 8 each
    {
        const float4* __restrict__ g4 = (const float4*)gtable;
        float4* t4 = (float4*)tab;
#pragma unroll
        for (int i = 0; i < (TN * 2 / 4) / BLOCK; ++i)
            t4[threadIdx.x + i * BLOCK] = g4[threadIdx.x + i * BLOCK];
    }
    __syncthreads();

    const float cw0 = conv_w[0], cw1 = conv_w[1], cw2 = conv_w[2], cw3 = conv_w[3];
    const float cb = conv_b[0];

    const float4* __restrict__ dp = data + (size_t)blockIdx.x * PER_BLOCK + threadIdx.x;
    float* __restrict__ op = out + (size_t)blockIdx.x * PER_BLOCK + threadIdx.x;

#pragma unroll 8
    for (int k = 0; k < ITERS; ++k) {
        float4 d = dp[k * BLOCK];
        float logit = fmaf(d.x, cw0, fmaf(d.y, cw1, fmaf(d.z, cw2, fmaf(d.w, cw3, cb))));
        float e = __expf(-logit);                    // v_exp path
        float act = __builtin_amdgcn_rcpf(1.0f + e); // sigmoid
        float t = act * (float)(TN - 1);             // t in [0, 4095]
        unsigned int i = (unsigned int)t;            // act>=0; i<=4095, tab[4095] valid
        float frac = t - (float)i;
        float2 yd = tab[i];                          // ds_read_b64
        op[k * BLOCK] = fmaf(frac, yd.y, yd.x);
    }
}

// Bounds-checked scalar tail (never launches when n % PER_BLOCK == 0).
__global__ __launch_bounds__(BLOCK)
void hybridconv_tail(const float4* __restrict__ data,
                     const float* __restrict__ conv_w,
                     const float* __restrict__ conv_b,
                     const float2* __restrict__ gtable,
                     float* __restrict__ out, int start, int n) {
    int idx = start + blockIdx.x * BLOCK + threadIdx.x;
    if (idx >= n) return;
    float4 d = data[idx];
    float logit = fmaf(d.x, conv_w[0], fmaf(d.y, conv_w[1],
                  fmaf(d.z, conv_w[2], fmaf(d.w, conv_w[3], conv_b[0]))));
    float e = __expf(-logit);
    float act = __builtin_amdgcn_rcpf(1.0f + e);
    float t = act * (float)(TN - 1);
    unsigned int i = (unsigned int)t;
    i = min(i, (unsigned int)(TN - 1));
    float frac = t - (float)i;
    float2 yd = gtable[i];
    out[idx] = fmaf(frac, yd.y, yd.x);
}

extern "C" void kernel_launch(void* const* d_in, const int* in_sizes, int n_in,
                              void* d_out, int out_size, void* d_ws, size_t ws_size,
                              hipStream_t stream) {
    const float4* data  = (const float4*)d_in[0];
    const float* conv_w = (const float*)d_in[1];
    const float* conv_b = (const float*)d_in[2];
    const float* basis  = (const float*)d_in[3];
    const float* w1     = (const float*)d_in[4];
    const float* b1     = (const float*)d_in[5];
    const float* w2     = (const float*)d_in[6];
    const float* b2     = (const float*)d_in[7];
    float* out = (float*)d_out;
    float2* table = (float2*)d_ws;   // 32 KB scratch

    int n = out_size;  // N patches, one output each

    fill_table_kernel<<<dim3(TN / BLOCK), dim3(BLOCK), 0, stream>>>(
        basis, w1, b1, w2, b2, table);

    int full_blocks = n / PER_BLOCK;               // 1024 for N=8388608
    if (full_blocks > 0) {
        hybridconv_main<<<dim3(full_blocks), dim3(BLOCK), 0, stream>>>(
            data, conv_w, conv_b, table, out);
    }
    int start = full_blocks * PER_BLOCK;
    if (start < n) {                               // never taken for N=8388608
        int rem = n - start;
        hybridconv_tail<<<dim3((rem + BLOCK - 1) / BLOCK), dim3(BLOCK), 0, stream>>>(
            data, conv_w, conv_b, table, out, start, n);
    }
}

// Round 3
// 221.045 us; speedup vs baseline: 1.0355x; 1.0030x over previous
//
#include <hip/hip_runtime.h>

// g(act) lookup: TN uniform nodes over act=[0,1], table[i] = g(i/(TN-1)).
// Table has TN+1 entries so the hot loop's tab[i+1] read is valid at i=TN-1
// (act==1.0 -> frac==0, the extra entry's value is never weighted in).
#define TN 4096
#define TABN (TN + 1)
#define BLOCK 256
#define ITERS 32                  // patches per thread in main kernel
#define PER_BLOCK (BLOCK * ITERS) // 8192 patches per block

// Full reference math for one scalar activation value (runs only TABN times).
__device__ float eval_g(float act,
                        const float* __restrict__ basis,
                        const float* __restrict__ w1,
                        const float* __restrict__ b1,
                        const float* __restrict__ w2,
                        const float* __restrict__ b2) {
    float feats[8];
#pragma unroll
    for (int b = 0; b < 8; ++b) {
        float s = 0.f;
#pragma unroll
        for (int k = 0; k < 4; ++k) {
            float d = act - basis[b * 4 + k];
            s = fmaf(d, d, s);
        }
        feats[b] = __expf(-s);   // GAMMA = 1
    }
    float out = b2[0];
#pragma unroll
    for (int j = 0; j < 16; ++j) {
        float u = b1[j];
#pragma unroll
        for (int b = 0; b < 8; ++b) u = fmaf(feats[b], w1[b * 16 + j], u);
        out = fmaf(tanhf(u), w2[j], out);
    }
    return out;
}

__global__ __launch_bounds__(BLOCK)
void fill_table_kernel(const float* __restrict__ basis,
                       const float* __restrict__ w1,
                       const float* __restrict__ b1,
                       const float* __restrict__ w2,
                       const float* __restrict__ b2,
                       float* __restrict__ table) {
    int i = blockIdx.x * BLOCK + threadIdx.x;
    if (i >= TABN) return;
    const float inv = 1.0f / (float)(TN - 1);
    int node = (i < TN) ? i : (TN - 1);     // entry TN repeats the last node
    float a = (float)node * inv;
    table[i] = eval_g(a, basis, w1, b1, w2, b2);
}

// Hot kernel: grid covers exactly gridDim.x*PER_BLOCK patches (no bounds
// check). Remainder patches handled by hybridconv_tail (not taken at N=8.4M).
__global__ __launch_bounds__(BLOCK)
void hybridconv_main(const float4* __restrict__ data,
                     const float* __restrict__ conv_w,
                     const float* __restrict__ conv_b,
                     const float* __restrict__ gtable,
                     float* __restrict__ out) {
    __shared__ __align__(16) float tab[TABN];
    // cooperative table copy, float4-wide: 1024 float4 / 256 threads = 4 each
    {
        const float4* __restrict__ g4 = (const float4*)gtable;
        float4* t4 = (float4*)tab;
#pragma unroll
        for (int i = 0; i < (TN / 4) / BLOCK; ++i)
            t4[threadIdx.x + i * BLOCK] = g4[threadIdx.x + i * BLOCK];
        if (threadIdx.x == 0) tab[TN] = gtable[TN];
    }
    __syncthreads();

    const float cw0 = conv_w[0], cw1 = conv_w[1], cw2 = conv_w[2], cw3 = conv_w[3];
    const float cb = conv_b[0];

    const float4* __restrict__ dp = data + (size_t)blockIdx.x * PER_BLOCK + threadIdx.x;
    float* __restrict__ op = out + (size_t)blockIdx.x * PER_BLOCK + threadIdx.x;

#pragma unroll 8
    for (int k = 0; k < ITERS; ++k) {
        float4 d = dp[k * BLOCK];
        float logit = fmaf(d.x, cw0, fmaf(d.y, cw1, fmaf(d.z, cw2, fmaf(d.w, cw3, cb))));
        float e = __expf(-logit);                    // v_exp path
        float act = __builtin_amdgcn_rcpf(1.0f + e); // sigmoid
        float t = act * (float)(TN - 1);             // t in [0, 4095]
        unsigned int i = (unsigned int)t;            // act>=0; i<=4095
        float frac = t - (float)i;
        float y0 = tab[i];                           // ds_read2_b32 pair
        float y1 = tab[i + 1];
        float r = fmaf(frac, y1 - y0, y0);
        __builtin_nontemporal_store(r, &op[k * BLOCK]);  // out is never re-read
    }
}

// Bounds-checked scalar tail (never launches when n % PER_BLOCK == 0).
__global__ __launch_bounds__(BLOCK)
void hybridconv_tail(const float4* __restrict__ data,
                     const float* __restrict__ conv_w,
                     const float* __restrict__ conv_b,
                     const float* __restrict__ gtable,
                     float* __restrict__ out, int start, int n) {
    int idx = start + blockIdx.x * BLOCK + threadIdx.x;
    if (idx >= n) return;
    float4 d = data[idx];
    float logit = fmaf(d.x, conv_w[0], fmaf(d.y, conv_w[1],
                  fmaf(d.z, conv_w[2], fmaf(d.w, conv_w[3], conv_b[0]))));
    float e = __expf(-logit);
    float act = __builtin_amdgcn_rcpf(1.0f + e);
    float t = act * (float)(TN - 1);
    unsigned int i = (unsigned int)t;
    i = min(i, (unsigned int)(TN - 1));
    float frac = t - (float)i;
    float y0 = gtable[i];
    float y1 = gtable[i + 1];
    out[idx] = fmaf(frac, y1 - y0, y0);
}

extern "C" void kernel_launch(void* const* d_in, const int* in_sizes, int n_in,
                              void* d_out, int out_size, void* d_ws, size_t ws_size,
                              hipStream_t stream) {
    const float4* data  = (const float4*)d_in[0];
    const float* conv_w = (const float*)d_in[1];
    const float* conv_b = (const float*)d_in[2];
    const float* basis  = (const float*)d_in[3];
    const float* w1     = (const float*)d_in[4];
    const float* b1     = (const float*)d_in[5];
    const float* w2     = (const float*)d_in[6];
    const float* b2     = (const float*)d_in[7];
    float* out = (float*)d_out;
    float* table = (float*)d_ws;   // 16.4 KB scratch

    int n = out_size;  // N patches, one output each

    fill_table_kernel<<<dim3((TABN + BLOCK - 1) / BLOCK), dim3(BLOCK), 0, stream>>>(
        basis, w1, b1, w2, b2, table);

    int full_blocks = n / PER_BLOCK;               // 1024 for N=8388608
    if (full_blocks > 0) {
        hybridconv_main<<<dim3(full_blocks), dim3(BLOCK), 0, stream>>>(
            data, conv_w, conv_b, table, out);
    }
    int start = full_blocks * PER_BLOCK;
    if (start < n) {                               // never taken for N=8388608
        int rem = n - start;
        hybridconv_tail<<<dim3((rem + BLOCK - 1) / BLOCK), dim3(BLOCK), 0, stream>>>(
            data, conv_w, conv_b, table, out, start, n);
    }
}